// Round 1
// baseline (306.571 us; speedup 1.0000x reference)
//
#include <hip/hip_runtime.h>
#include <hip/hip_bf16.h>

#define DEV __device__ __forceinline__

typedef __attribute__((ext_vector_type(4))) float f32x4;
typedef __bf16 bf16x8 __attribute__((ext_vector_type(8)));

static DEV unsigned short f2bf(float f) {
    union { float f; unsigned u; } x; x.f = f;
    unsigned r = x.u + 0x7fffu + ((x.u >> 16) & 1u);
    return (unsigned short)(r >> 16);
}

static DEV f32x4 zero4() { f32x4 v; v[0] = 0.f; v[1] = 0.f; v[2] = 0.f; v[3] = 0.f; return v; }

// ---------------- conversion kernels ----------------

__global__ void k_cvt_bf16(const float* __restrict__ in, unsigned short* __restrict__ out, int n4) {
    int i = blockIdx.x * blockDim.x + threadIdx.x;
    if (i >= n4) return;
    float4 v = reinterpret_cast<const float4*>(in)[i];
    ushort4 o;
    o.x = f2bf(v.x); o.y = f2bf(v.y); o.z = f2bf(v.z); o.w = f2bf(v.w);
    reinterpret_cast<ushort4*>(out)[i] = o;
}

// in [K][N] f32 -> out [N][K] bf16
__global__ void k_transpose_bf16(const float* __restrict__ in, unsigned short* __restrict__ out, int K, int N) {
    int i = blockIdx.x * blockDim.x + threadIdx.x;
    if (i >= K * N) return;
    int n = i / K, k = i - n * K;
    out[i] = f2bf(in[(size_t)k * N + n]);
}

// ---------------- GEMM: C[M,N] = A[M,384] * B^T  (B stored [N][384]) ----------------
// EPI==0: QKV epilogue -> scatter Q(scaled), K as [B,H,T,D], V as [B,H,D,T], all bf16
// EPI==1: out = acc + bias, f32

template <int EPI>
__global__ __launch_bounds__(256) void k_gemm(
    const unsigned short* __restrict__ A,
    const unsigned short* __restrict__ B,
    unsigned short* __restrict__ Qb, unsigned short* __restrict__ Kb, unsigned short* __restrict__ Vtb,
    const float* __restrict__ bias, float* __restrict__ Out)
{
    const int K = 384;
    __shared__ unsigned short lA[128][72];
    __shared__ unsigned short lB[128][72];

    int tid = threadIdx.x;
    int m0 = blockIdx.x * 128;
    int n0 = blockIdx.y * 128;
    int w = tid >> 6, lane = tid & 63;
    int wm = (w >> 1) * 64, wn = (w & 1) * 64;
    int lr = lane & 15, lg = lane >> 4;

    f32x4 acc[4][4];
#pragma unroll
    for (int i = 0; i < 4; i++)
#pragma unroll
        for (int j = 0; j < 4; j++) acc[i][j] = zero4();

    int srow = tid >> 3, scol = (tid & 7) * 8;

    for (int kb = 0; kb < K; kb += 64) {
        __syncthreads();
#pragma unroll
        for (int p = 0; p < 4; ++p) {
            int r = srow + p * 32;
            *(uint4*)&lA[r][scol] = *(const uint4*)&A[(size_t)(m0 + r) * K + kb + scol];
            *(uint4*)&lB[r][scol] = *(const uint4*)&B[(size_t)(n0 + r) * K + kb + scol];
        }
        __syncthreads();

        bf16x8 af[4][2], bfr[4][2];
#pragma unroll
        for (int kc = 0; kc < 2; ++kc) {
#pragma unroll
            for (int t = 0; t < 4; ++t) {
                af[t][kc]  = *(const bf16x8*)&lA[wm + t * 16 + lr][kc * 32 + lg * 8];
                bfr[t][kc] = *(const bf16x8*)&lB[wn + t * 16 + lr][kc * 32 + lg * 8];
            }
        }
#pragma unroll
        for (int kc = 0; kc < 2; ++kc)
#pragma unroll
            for (int mt = 0; mt < 4; ++mt)
#pragma unroll
                for (int nt = 0; nt < 4; ++nt)
                    acc[mt][nt] = __builtin_amdgcn_mfma_f32_16x16x32_bf16(af[mt][kc], bfr[nt][kc], acc[mt][nt], 0, 0, 0);
    }

#pragma unroll
    for (int mt = 0; mt < 4; ++mt) {
#pragma unroll
        for (int nt = 0; nt < 4; ++nt) {
#pragma unroll
            for (int r = 0; r < 4; ++r) {
                int row = m0 + wm + mt * 16 + lg * 4 + r;
                int col = n0 + wn + nt * 16 + lr;
                float v = acc[mt][nt][r];
                if (EPI == 0) {
                    int which = col / 384;
                    int c = col - which * 384;
                    int hh = c >> 6, d = c & 63;
                    int bb = row >> 10, t = row & 1023;
                    size_t bh = (size_t)bb * 6 + hh;
                    if (which == 0)      Qb[(bh * 1024 + t) * 64 + d] = f2bf(v * 0.125f);
                    else if (which == 1) Kb[(bh * 1024 + t) * 64 + d] = f2bf(v);
                    else                 Vtb[(bh * 64 + d) * 1024 + t] = f2bf(v);
                } else {
                    Out[(size_t)row * 384 + col] = v + bias[col];
                }
            }
        }
    }
}

// ---------------- flash attention ----------------
// grid (16 qtiles, 192 bh); block 256 = 4 waves, each wave owns 16 q-rows.
__global__ __launch_bounds__(256) void k_attn(
    const unsigned short* __restrict__ Q,
    const unsigned short* __restrict__ Kp,
    const unsigned short* __restrict__ Vt,
    unsigned short* __restrict__ Y)
{
    __shared__ unsigned short lK[64][72];
    __shared__ unsigned short lV[64][72];   // Vt tile: [d][k]
    __shared__ unsigned short lP[4][16][72];

    int qt = blockIdx.x;
    int bh = blockIdx.y;
    int b = bh / 6, h = bh - b * 6;
    int tid = threadIdx.x;
    int w = tid >> 6, lane = tid & 63;
    int lr = lane & 15, lg = lane >> 4;
    int qw = qt * 64 + w * 16;

    const size_t bhT = (size_t)bh * 1024;

    bf16x8 qf[2];
#pragma unroll
    for (int kc = 0; kc < 2; ++kc)
        qf[kc] = *(const bf16x8*)&Q[(bhT + qw + lr) * 64 + kc * 32 + lg * 8];

    f32x4 o[4];
    float mr[4], lsum[4];
#pragma unroll
    for (int i = 0; i < 4; i++) { o[i] = zero4(); mr[i] = -1e30f; lsum[i] = 0.f; }

    int srow = tid >> 3, scol = (tid & 7) * 8;

    for (int kt = 0; kt <= qt; ++kt) {
        __syncthreads();
#pragma unroll
        for (int p = 0; p < 2; ++p) {
            int r = srow + p * 32;
            *(uint4*)&lK[r][scol] = *(const uint4*)&Kp[(bhT + kt * 64 + r) * 64 + scol];
            *(uint4*)&lV[r][scol] = *(const uint4*)&Vt[((size_t)bh * 64 + r) * 1024 + kt * 64 + scol];
        }
        __syncthreads();

        f32x4 s[4];
#pragma unroll
        for (int nt = 0; nt < 4; ++nt) {
            s[nt] = zero4();
#pragma unroll
            for (int kc = 0; kc < 2; ++kc) {
                bf16x8 kf = *(const bf16x8*)&lK[nt * 16 + lr][kc * 32 + lg * 8];
                s[nt] = __builtin_amdgcn_mfma_f32_16x16x32_bf16(qf[kc], kf, s[nt], 0, 0, 0);
            }
        }
        if (kt == qt) {
#pragma unroll
            for (int nt = 0; nt < 4; ++nt) {
                int kl = nt * 16 + lr;
#pragma unroll
                for (int r = 0; r < 4; ++r) {
                    int ql = w * 16 + lg * 4 + r;
                    if (kl > ql) s[nt][r] = -1e30f;
                }
            }
        }
        float al[4];
#pragma unroll
        for (int r = 0; r < 4; ++r) {
            float mx = fmaxf(fmaxf(s[0][r], s[1][r]), fmaxf(s[2][r], s[3][r]));
#pragma unroll
            for (int off = 1; off < 16; off <<= 1) mx = fmaxf(mx, __shfl_xor(mx, off, 16));
            float mn = fmaxf(mr[r], mx);
            al[r] = __expf(mr[r] - mn);
            mr[r] = mn;
            float rs = 0.f;
#pragma unroll
            for (int nt = 0; nt < 4; ++nt) {
                float p = __expf(s[nt][r] - mn);
                s[nt][r] = p;
                rs += p;
            }
#pragma unroll
            for (int off = 1; off < 16; off <<= 1) rs += __shfl_xor(rs, off, 16);
            lsum[r] = lsum[r] * al[r] + rs;
        }
        // write P (bf16) to wave-private LDS for A-fragment relayout
#pragma unroll
        for (int nt = 0; nt < 4; ++nt)
#pragma unroll
            for (int r = 0; r < 4; ++r)
                lP[w][lg * 4 + r][nt * 16 + lr] = f2bf(s[nt][r]);
#pragma unroll
        for (int nt = 0; nt < 4; ++nt)
#pragma unroll
            for (int r = 0; r < 4; ++r)
                o[nt][r] *= al[r];

        bf16x8 pf[2];
#pragma unroll
        for (int kc = 0; kc < 2; ++kc)
            pf[kc] = *(const bf16x8*)&lP[w][lr][kc * 32 + lg * 8];
#pragma unroll
        for (int nt = 0; nt < 4; ++nt) {
#pragma unroll
            for (int kc = 0; kc < 2; ++kc) {
                bf16x8 vf = *(const bf16x8*)&lV[nt * 16 + lr][kc * 32 + lg * 8];
                o[nt] = __builtin_amdgcn_mfma_f32_16x16x32_bf16(pf[kc], vf, o[nt], 0, 0, 0);
            }
        }
    }

#pragma unroll
    for (int nt = 0; nt < 4; ++nt) {
#pragma unroll
        for (int r = 0; r < 4; ++r) {
            int qrow = qw + lg * 4 + r;
            int col = h * 64 + nt * 16 + lr;
            Y[((size_t)b * 1024 + qrow) * 384 + col] = f2bf(o[nt][r] / lsum[r]);
        }
    }
}

// ---------------- launcher ----------------

extern "C" void kernel_launch(void* const* d_in, const int* in_sizes, int n_in,
                              void* d_out, int out_size, void* d_ws, size_t ws_size,
                              hipStream_t stream)
{
    const float* x  = (const float*)d_in[0];
    const float* Wa = (const float*)d_in[1];
    const float* Wp = (const float*)d_in[2];
    const float* bp = (const float*)d_in[3];
    float* out = (float*)d_out;

    char* ws = (char*)d_ws;
    unsigned short* xb  = (unsigned short*)(ws);              // 25165824 B; reused as Y after GEMM-A
    unsigned short* WaT = (unsigned short*)(ws + 25165824);   // 884736 B
    unsigned short* WpT = (unsigned short*)(ws + 26050560);   // 294912 B
    unsigned short* Qb  = (unsigned short*)(ws + 26345472);   // 25165824 B
    unsigned short* Kb  = (unsigned short*)(ws + 51511296);   // 25165824 B
    unsigned short* Vtb = (unsigned short*)(ws + 76677120);   // 25165824 B
    // total: 101842944 B

    k_cvt_bf16<<<12288, 256, 0, stream>>>(x, xb, 3145728);
    k_transpose_bf16<<<1728, 256, 0, stream>>>(Wa, WaT, 384, 1152);
    k_transpose_bf16<<<576, 256, 0, stream>>>(Wp, WpT, 384, 384);

    k_gemm<0><<<dim3(256, 9), 256, 0, stream>>>(xb, WaT, Qb, Kb, Vtb, nullptr, nullptr);
    k_attn<<<dim3(16, 192), 256, 0, stream>>>(Qb, Kb, Vtb, xb);
    k_gemm<1><<<dim3(256, 3), 256, 0, stream>>>(xb, WpT, nullptr, nullptr, nullptr, bp, out);
}